// Round 11
// baseline (299.546 us; speedup 1.0000x reference)
//
#include <hip/hip_runtime.h>
#include <stdint.h>

#define B_ 8
#define S_ 2048
#define D_ 512
#define U_ 512
#define M_TOTAL (B_*S_)   // 16384
#define NPROJ (2*U_)      // 1024
#define QBLK 64
#define KVBLK 64
#define NIT (S_/KVBLK)    // 32
#define LOG2E 1.4426950408889634f

typedef __attribute__((ext_vector_type(8))) _Float16 f16x8;
typedef __attribute__((ext_vector_type(4))) float f32x4;
typedef __attribute__((ext_vector_type(16))) float f32x16;

__device__ __forceinline__ uint16_t f2h(float f){
  return __builtin_bit_cast(uint16_t, (_Float16)f);
}

__device__ __forceinline__ void gload16(const void* g, void* l){
  __builtin_amdgcn_global_load_lds(
      (const __attribute__((address_space(1))) void*)g,
      (__attribute__((address_space(3))) void*)l, 16, 0, 0);
}

// Stage one half-tile [ROWS x 64] f16 into linear LDS, global source pre-swizzled.
template<int ROWS>
__device__ __forceinline__ void stage_half(char* lbase, const uint16_t* __restrict__ gpanel,
                                           int ld, int wv, int lane){
  int r0 = wv*8 + (lane>>3);
  int gs = ((lane&7) ^ (r0&7)) << 3;
  gload16(gpanel + (size_t)r0*ld + gs, lbase + wv*1024);
  if constexpr (ROWS==128){
    gload16(gpanel + (size_t)(r0+64)*ld + gs, lbase + 8192 + wv*1024);
  }
}

// ---- prep: WT[u][d] = f16(W[d][u]); u<512 -> Ww, else Uw ----
__global__ __launch_bounds__(256) void prep_w(const float* __restrict__ Ww,
                                              const float* __restrict__ Uw,
                                              uint16_t* __restrict__ WT){
  int idx = blockIdx.x*256 + threadIdx.x;
  int u = idx >> 9;
  int d = idx & 511;
  float v = (u < U_) ? Ww[d*U_ + u] : Uw[d*U_ + (u-U_)];
  WT[idx] = f2h(v);
}

// ---- prep: Xf[b][s][d] f16 row-major; XT[b][d][s] f16 transposed ----
__global__ __launch_bounds__(256) void prep_x(const float* __restrict__ X,
                                              uint16_t* __restrict__ Xf,
                                              uint16_t* __restrict__ XT){
  __shared__ float tile[32][33];
  int b = blockIdx.z;
  int s0 = blockIdx.x * 32;
  int d0 = blockIdx.y * 32;
  int tid = threadIdx.x;
  int tr = tid >> 5;
  int tc = tid & 31;
  const float* Xb = X + (size_t)b*S_*D_;
#pragma unroll
  for (int i = 0; i < 32; i += 8){
    size_t off = (size_t)(s0+tr+i)*D_ + d0+tc;
    float v = Xb[off];
    tile[tr+i][tc] = v;
    Xf[(size_t)b*S_*D_ + off] = f2h(v);
  }
  __syncthreads();
  uint16_t* XTb = XT + (size_t)b*D_*S_;
#pragma unroll
  for (int i = 0; i < 32; i += 8)
    XTb[(size_t)(d0+tr+i)*S_ + s0+tc] = f2h(tile[tc][tr+i]);
}

// ---- 8-phase NT projection GEMM; Q output pre-scaled by log2(e) ----
__global__ __launch_bounds__(512, 2) void gemm_proj(
    const uint16_t* __restrict__ A, int lda,
    const uint16_t* __restrict__ Bp, int ldb,
    uint16_t* __restrict__ Qo, uint16_t* __restrict__ Ko,
    const float* __restrict__ biasW, const float* __restrict__ biasU,
    int KD)
{
  constexpr int AHALF = 128*128;
  constexpr int BHALF = 128*128;
  constexpr int DSTR  = 2*AHALF + 2*BHALF;
  __shared__ __align__(16) char smem[2*DSTR];

  const int m0 = blockIdx.y * 256;
  const int n0 = blockIdx.x * 256;
  const uint16_t* Apan = A  + (size_t)m0*lda;
  const uint16_t* Bpan = Bp + (size_t)n0*ldb;

  const int t512 = threadIdx.x;
  const int wv   = t512 >> 6;
  const int lane = t512 & 63;
  const int wm   = wv >> 2;
  const int wn   = wv & 3;
  const int fr   = lane & 15;
  const int fg   = lane >> 4;
  const int sw   = fr & 7;

  const int NT = KD >> 6;

  auto Aslot = [&](int par, int h){ return smem + par*DSTR + h*AHALF; };
  auto Bslot = [&](int par, int h){ return smem + par*DSTR + 2*AHALF + h*BHALF; };

  stage_half<128>(Aslot(0,0), Apan,                   lda, wv, lane);
  stage_half<128>(Aslot(0,1), Apan + (size_t)128*lda, lda, wv, lane);
  stage_half<128>(Bslot(0,0), Bpan,                   ldb, wv, lane);
  stage_half<128>(Bslot(0,1), Bpan + (size_t)128*ldb, ldb, wv, lane);
  if (NT > 1)
    stage_half<128>(Aslot(1,0), Apan + 64,            lda, wv, lane);
  asm volatile("s_waitcnt vmcnt(2)" ::: "memory");
  __builtin_amdgcn_s_barrier();

  f32x4 acc[8][4];
#pragma unroll
  for (int i=0;i<8;i++)
#pragma unroll
    for (int j=0;j<4;j++) acc[i][j] = (f32x4){0.f,0.f,0.f,0.f};

  for (int t = 0; t < NT; ++t){
    const int p = t & 1;
    const char* myA = Aslot(p, wm);
    const char* myB = Bslot(p, wn>>1);
    f16x8 af[8];

    auto rdA = [&](int ks){
#pragma unroll
      for (int mf=0; mf<8; ++mf)
        af[mf] = *(const f16x8*)(myA + (mf*16+fr)*128 + (((ks<<2)|fg) ^ sw)*16);
    };
    auto rdB = [&](int ks, int nh, f16x8& b0, f16x8& b1){
      int rb = (wn&1)*64 + nh*32 + fr;
      b0 = *(const f16x8*)(myB + rb*128      + (((ks<<2)|fg) ^ sw)*16);
      b1 = *(const f16x8*)(myB + (rb+16)*128 + (((ks<<2)|fg) ^ sw)*16);
    };
    auto mm = [&](int nh, f16x8 b0, f16x8 b1){
      __builtin_amdgcn_s_setprio(1);
#pragma unroll
      for (int mf=0; mf<8; ++mf){
        acc[mf][nh*2]   = __builtin_amdgcn_mfma_f32_16x16x32_f16(af[mf], b0, acc[mf][nh*2],   0,0,0);
        acc[mf][nh*2+1] = __builtin_amdgcn_mfma_f32_16x16x32_f16(af[mf], b1, acc[mf][nh*2+1], 0,0,0);
      }
      __builtin_amdgcn_s_setprio(0);
    };

    f16x8 b0, b1;
    rdA(0); rdB(0, 0, b0, b1);
    if (t+1 < NT)
      stage_half<128>(Aslot(p^1,1), Apan + (size_t)128*lda + (t+1)*64, lda, wv, lane);
    __builtin_amdgcn_s_barrier();
    mm(0, b0, b1);
    __builtin_amdgcn_s_barrier();
    rdB(0, 1, b0, b1);
    if (t+1 < NT)
      stage_half<128>(Bslot(p^1,0), Bpan + (t+1)*64, ldb, wv, lane);
    __builtin_amdgcn_s_barrier();
    mm(1, b0, b1);
    __builtin_amdgcn_s_barrier();
    rdA(1); rdB(1, 0, b0, b1);
    if (t+1 < NT)
      stage_half<128>(Bslot(p^1,1), Bpan + (size_t)128*ldb + (t+1)*64, ldb, wv, lane);
    __builtin_amdgcn_s_barrier();
    mm(0, b0, b1);
    __builtin_amdgcn_s_barrier();
    rdB(1, 1, b0, b1);
    if (t+2 < NT)
      stage_half<128>(Aslot(p,0), Apan + (t+2)*64, lda, wv, lane);
    __builtin_amdgcn_s_barrier();
    mm(1, b0, b1);
    asm volatile("s_waitcnt vmcnt(2)" ::: "memory");
    __builtin_amdgcn_s_barrier();
  }

#pragma unroll
  for (int mf=0; mf<8; ++mf)
#pragma unroll
    for (int nf=0; nf<4; ++nf){
      int col  = n0 + wn*64 + nf*16 + fr;
      int rowb = m0 + wm*128 + mf*16 + fg*4;
      f32x4 a = acc[mf][nf];
      float bias = (col < U_) ? biasW[col] : biasU[col - U_];
      if (col < U_){
#pragma unroll
        for (int r=0;r<4;r++) Qo[(size_t)(rowb+r)*U_ + col] = f2h((a[r] + bias)*LOG2E);
      } else {
#pragma unroll
        for (int r=0;r<4;r++) Ko[(size_t)(rowb+r)*U_ + col - U_] = f2h(a[r] + bias);
      }
    }
}

// ---- fused flash attention v5: symmetric waves, both phases each ----
// 8 waves: QK role (nt=wv&1 q-slice, mt=(wv>>1)&1 kv-half; wv and wv+4 duplicate
//   benignly), PV role (nt q-slice, dq=wv>>1 d-quarter of 128; all 8 distinct).
// Per iter: preA { V(t-1)->reg issue | QK(t) mfma(K,Q) 32x32, pm_s |
//                  rescale + PV(t-1) }  barrier A
//           postA { K(t+1) restage | lane-local softmax, Ps/ps/f/flag }  barrier B
__global__ __launch_bounds__(512, 2) void flash_ws(
    const uint16_t* __restrict__ Qf,   // [B*S][512] f16 (pre-scaled by log2e)
    const uint16_t* __restrict__ Kf,   // [B*S][512] f16
    const uint16_t* __restrict__ XT,   // [B][512][2048] f16
    float* __restrict__ Out)           // [B*S][512] f32
{
  __shared__ __align__(16) uint16_t Qs[QBLK][512];    // 64 KB, swz g^=(row&31)
  __shared__ __align__(16) uint16_t Ks[KVBLK][512];   // 64 KB, swz g^=(row&31)
  __shared__ __align__(16) uint16_t Ps[QBLK][KVBLK];  // 8 KB,  swz g^=(q&7)
  __shared__ float pm_s[2][QBLK];                     // [mt][q] partial max
  __shared__ float ps_s[2][2][QBLK];                  // [buf][mt][q] partial sums
  __shared__ float f_s[2][QBLK];                      // [buf][q] rescale factor
  __shared__ float l_s[QBLK];
  __shared__ unsigned flag_s[2][2];                   // [buf][nt]

  const int bid   = blockIdx.x;
  const int batch = bid & 7;
  const int s0    = (bid >> 3) * QBLK;

  const int t512 = threadIdx.x;
  const int wv   = t512 >> 6;
  const int lane = t512 & 63;
  const int l31  = lane & 31;
  const int l5   = lane >> 5;
  const int nt = wv & 1;          // q-slice (both roles)
  const int mt = (wv >> 1) & 1;   // QK kv-half
  const int dq = wv >> 1;         // PV d-quarter (0..3)

  const uint16_t* Krow = Kf + (size_t)batch*S_*U_;
  const uint16_t* Vt   = XT + (size_t)batch*D_*S_;

  // ---- PV accumulators: 32q x 128d -> 64 f32 ----
  f32x16 acc[4];
#pragma unroll
  for (int nf=0; nf<4; ++nf)
#pragma unroll
    for (int r=0; r<16; ++r) acc[nf][r] = 0.f;

  float m_reg = -3.0e38f, l_reg = 0.f, f_reg = 1.f;

  // ---- prologue: stage Qs and Ks(0), all 512 threads, swizzled source ----
  {
    const uint16_t* Qb = Qf + ((size_t)batch*S_ + s0)*U_;
#pragma unroll
    for (int i=0; i<8; ++i){
      int c = i*512 + t512;
      int r = c >> 6, gl = c & 63;
      int gs = gl ^ (r & 31);
      gload16(Qb + (size_t)r*U_ + gs*8, (char*)Qs + (i*512 + wv*64)*16);
    }
#pragma unroll
    for (int i=0; i<8; ++i){
      int c = i*512 + t512;
      int r = c >> 6, gl = c & 63;
      int gs = gl ^ (r & 31);
      gload16(Krow + (size_t)r*U_ + gs*8, (char*)Ks + (i*512 + wv*64)*16);
    }
  }
  asm volatile("s_waitcnt vmcnt(0) lgkmcnt(0)" ::: "memory");
  __builtin_amdgcn_s_barrier();                       // Qs + K(0) certified
  __builtin_amdgcn_sched_barrier(0);

  for (int t = 0; t <= NIT; ++t){
    const int buf = t & 1, pbuf = buf ^ 1;
    float sv[16];

    // ---- l-update (all t>=1, incl. t==NIT) ----
    if (t >= 1){
      int q = nt*32 + l31;
      float s01 = ps_s[pbuf][0][q] + ps_s[pbuf][1][q];
      l_reg = l_reg * f_reg + s01;
    }

    // ================= pre-A segment =================
    // issue V(t-1) loads FIRST: they land under the QK phase
    f16x8 vb[4][4];
    if (t >= 1){
      const int it = t - 1;
#pragma unroll
      for (int kk=0; kk<4; ++kk)
#pragma unroll
        for (int nf=0; nf<4; ++nf){
          int d = dq*128 + nf*32 + l31;
          vb[kk][nf] = *(const f16x8*)(Vt + (size_t)d*S_ + it*KVBLK + kk*16 + 8*l5);
        }
    }

    if (t < NIT){
      // QK^T: A = K rows mt*32+l31, B = Q rows nt*32+l31 (swapped operands)
      f32x16 sA, sB;
#pragma unroll
      for (int r=0;r<16;++r){ sA[r]=0.f; sB[r]=0.f; }
      const char* Kb = (const char*)Ks + (mt*32 + l31)*1024;
      const char* Qb = (const char*)Qs + (nt*32 + l31)*1024;
      __builtin_amdgcn_s_setprio(1);
#pragma unroll
      for (int kk=0; kk<32; kk+=2){
        int g0 = (( kk   <<1)|l5) ^ l31;
        int g1 = (((kk+1)<<1)|l5) ^ l31;
        f16x8 k0 = *(const f16x8*)(Kb + g0*16);
        f16x8 q0 = *(const f16x8*)(Qb + g0*16);
        f16x8 k1 = *(const f16x8*)(Kb + g1*16);
        f16x8 q1 = *(const f16x8*)(Qb + g1*16);
        sA = __builtin_amdgcn_mfma_f32_32x32x16_f16(k0, q0, sA, 0,0,0);
        sB = __builtin_amdgcn_mfma_f32_32x32x16_f16(k1, q1, sB, 0,0,0);
      }
      __builtin_amdgcn_s_setprio(0);
#pragma unroll
      for (int r=0;r<16;++r) sv[r] = sA[r] + sB[r];
      float pmax = sv[0];
#pragma unroll
      for (int r=1;r<16;++r) pmax = fmaxf(pmax, sv[r]);
      pmax = fmaxf(pmax, __shfl_xor(pmax, 32));
      if (lane < 32) pm_s[mt][nt*32 + l31] = pmax;
    }

    if (t >= 1){
      // rescale on flag (written postA(t-1), certified at barrier B)
      unsigned flg = flag_s[pbuf][0] | flag_s[pbuf][1];
      if (flg){
#pragma unroll
        for (int rq=0; rq<4; ++rq){
          int q0 = nt*32 + 8*rq + 4*l5;
          float4 fx = *(const float4*)&f_s[pbuf][q0];
#pragma unroll
          for (int nf=0; nf<4; ++nf){
            acc[nf][rq*4+0] *= fx.x;
            acc[nf][rq*4+1] *= fx.y;
            acc[nf][rq*4+2] *= fx.z;
            acc[nf][rq*4+3] *= fx.w;
          }
        }
      }
      // PV: A = P (own q-slice) from Ps, B = vb
      __builtin_amdgcn_s_setprio(1);
#pragma unroll
      for (int kk=0; kk<4; ++kk){
        int q = nt*32 + l31;
        f16x8 pa = *(const f16x8*)((const char*)Ps + q*128
                                   + ((((kk<<1)|l5) ^ (q&7))<<4));
#pragma unroll
        for (int nf=0; nf<4; ++nf)
          acc[nf] = __builtin_amdgcn_mfma_f32_32x32x16_f16(pa, vb[kk][nf], acc[nf], 0,0,0);
      }
      __builtin_amdgcn_s_setprio(0);
    }
    asm volatile("s_waitcnt lgkmcnt(0)" ::: "memory");
    __builtin_amdgcn_s_barrier();                     // A: pm published, Ps/Ks reads done
    __builtin_amdgcn_sched_barrier(0);

    // ================= post-A segment =================
    if (t < NIT){
      // restage K(t+1) over Ks (single buffer: all reads done at A)
      if (t+1 < NIT){
#pragma unroll
        for (int i=0; i<8; ++i){
          int c = i*512 + t512;
          int r = c >> 6, gl = c & 63;
          int gs = gl ^ (r & 31);
          gload16(Krow + (size_t)((t+1)*KVBLK + r)*U_ + gs*8,
                  (char*)Ks + (i*512 + wv*64)*16);
        }
      }
      const int q = nt*32 + l31;
      float pm = fmaxf(pm_s[0][q], pm_s[1][q]);
      bool chg = pm > m_reg + 11.54f;                 // defer-max (log2 units)
      unsigned anychg = __any(chg) ? 1u : 0u;
      float mn = chg ? pm : m_reg;
      f_reg = __builtin_amdgcn_exp2f(m_reg - mn);
      m_reg = mn;
      float p[16];
      float psum = 0.f;
#pragma unroll
      for (int r=0;r<16;++r){ p[r] = __builtin_amdgcn_exp2f(sv[r] - mn); psum += p[r]; }
      psum += __shfl_xor(psum, 32);
      // write P at true kv addresses (C/D row formula), swizzled by q&7
#pragma unroll
      for (int q4=0; q4<4; ++q4)
#pragma unroll
        for (int pp=0; pp<2; ++pp){
          uint32_t w = (uint32_t)f2h(p[q4*4+2*pp]) | ((uint32_t)f2h(p[q4*4+2*pp+1])<<16);
          int g = (mt*4 + q4) ^ (q & 7);
          *(uint32_t*)((char*)Ps + q*128 + g*16 + 8*l5 + 4*pp) = w;
        }
      if (lane < 32){
        ps_s[buf][mt][q] = psum;
        if (mt == 0) f_s[buf][q] = f_reg;
      }
      if (mt == 0 && lane == 0) flag_s[buf][nt] = anychg;
      asm volatile("s_waitcnt lgkmcnt(0)" ::: "memory");
      asm volatile("s_waitcnt vmcnt(0)" ::: "memory");  // K(t+1) landed
    }
    __builtin_amdgcn_s_barrier();                     // B: P/f/sums + K(t+1) certified
    __builtin_amdgcn_sched_barrier(0);
  }

  // ---- epilogue: publish final l; all waves normalize + store own (nt,dq) ----
  if (mt == 0 && lane < 32) l_s[nt*32 + l31] = l_reg;
  asm volatile("s_waitcnt lgkmcnt(0)" ::: "memory");
  __builtin_amdgcn_s_barrier();

  {
    float* Ob = Out + ((size_t)batch*S_ + s0)*D_;
#pragma unroll
    for (int rq=0; rq<4; ++rq){
      int q0 = nt*32 + 8*rq + 4*l5;
      float4 lv = *(const float4*)&l_s[q0];
      float4 li = make_float4(1.f/lv.x, 1.f/lv.y, 1.f/lv.z, 1.f/lv.w);
#pragma unroll
      for (int nf=0; nf<4; ++nf){
        int d = dq*128 + nf*32 + l31;
        Ob[(size_t)(q0+0)*D_ + d] = acc[nf][rq*4+0] * li.x;
        Ob[(size_t)(q0+1)*D_ + d] = acc[nf][rq*4+1] * li.y;
        Ob[(size_t)(q0+2)*D_ + d] = acc[nf][rq*4+2] * li.z;
        Ob[(size_t)(q0+3)*D_ + d] = acc[nf][rq*4+3] * li.w;
      }
    }
  }
}

extern "C" void kernel_launch(void* const* d_in, const int* in_sizes, int n_in,
                              void* d_out, int out_size, void* d_ws, size_t ws_size,
                              hipStream_t stream)
{
  (void)in_sizes; (void)n_in; (void)out_size; (void)ws_size;
  const float* X  = (const float*)d_in[0];
  const float* Ww = (const float*)d_in[1];
  const float* Wb = (const float*)d_in[2];
  const float* Uw = (const float*)d_in[3];
  const float* Ub = (const float*)d_in[4];
  float* out = (float*)d_out;

  char* ws = (char*)d_ws;
  size_t off = 0;
  uint16_t* Xf = (uint16_t*)(ws + off); off += (size_t)M_TOTAL*D_*2;  // f16 [M][512]
  uint16_t* XT = (uint16_t*)(ws + off); off += (size_t)B_*D_*S_*2;    // f16 [B][512][2048]
  uint16_t* WT = (uint16_t*)(ws + off); off += (size_t)NPROJ*D_*2;    // f16 [1024][512]
  uint16_t* Qf = (uint16_t*)(ws + off); off += (size_t)M_TOTAL*U_*2;  // f16 [M][512]
  uint16_t* Kf = (uint16_t*)(ws + off); off += (size_t)M_TOTAL*U_*2;

  prep_w<<<dim3((NPROJ*D_)/256), 256, 0, stream>>>(Ww, Uw, WT);
  prep_x<<<dim3(S_/32, D_/32, B_), 256, 0, stream>>>(X, Xf, XT);

  gemm_proj<<<dim3(NPROJ/256, M_TOTAL/256, 1), 512, 0, stream>>>(
      Xf, D_, WT, D_, Qf, Kf, Wb, Ub, D_);

  flash_ws<<<dim3(B_ * (S_/QBLK)), 512, 0, stream>>>(Qf, Kf, XT, out);
}

// Round 12
// 181.784 us; speedup vs baseline: 1.6478x; 1.6478x over previous
//
#include <hip/hip_runtime.h>
#include <stdint.h>

#define B_ 8
#define S_ 2048
#define D_ 512
#define U_ 512
#define M_TOTAL (B_*S_)   // 16384
#define NPROJ (2*U_)      // 1024
#define QBLK 64
#define KVBLK 64
#define NIT (S_/KVBLK)    // 32
#define LOG2E 1.4426950408889634f

typedef __attribute__((ext_vector_type(8))) _Float16 f16x8;
typedef __attribute__((ext_vector_type(4))) float f32x4;

__device__ __forceinline__ uint16_t f2h(float f){
  return __builtin_bit_cast(uint16_t, (_Float16)f);
}

__device__ __forceinline__ void gload16(const void* g, void* l){
  __builtin_amdgcn_global_load_lds(
      (const __attribute__((address_space(1))) void*)g,
      (__attribute__((address_space(3))) void*)l, 16, 0, 0);
}

// Stage one half-tile [ROWS x 64] f16 into linear LDS, global source pre-swizzled.
template<int ROWS>
__device__ __forceinline__ void stage_half(char* lbase, const uint16_t* __restrict__ gpanel,
                                           int ld, int wv, int lane){
  int r0 = wv*8 + (lane>>3);
  int gs = ((lane&7) ^ (r0&7)) << 3;
  gload16(gpanel + (size_t)r0*ld + gs, lbase + wv*1024);
  if constexpr (ROWS==128){
    gload16(gpanel + (size_t)(r0+64)*ld + gs, lbase + 8192 + wv*1024);
  }
}

// ---- prep: WT[u][d] = f16(W[d][u]); u<512 -> Ww, else Uw ----
__global__ __launch_bounds__(256) void prep_w(const float* __restrict__ Ww,
                                              const float* __restrict__ Uw,
                                              uint16_t* __restrict__ WT){
  int idx = blockIdx.x*256 + threadIdx.x;
  int u = idx >> 9;
  int d = idx & 511;
  float v = (u < U_) ? Ww[d*U_ + u] : Uw[d*U_ + (u-U_)];
  WT[idx] = f2h(v);
}

// ---- prep: Xf[b][s][d] f16 row-major; XT[b][d][s] f16 transposed ----
__global__ __launch_bounds__(256) void prep_x(const float* __restrict__ X,
                                              uint16_t* __restrict__ Xf,
                                              uint16_t* __restrict__ XT){
  __shared__ float tile[32][33];
  int b = blockIdx.z;
  int s0 = blockIdx.x * 32;
  int d0 = blockIdx.y * 32;
  int tid = threadIdx.x;
  int tr = tid >> 5;
  int tc = tid & 31;
  const float* Xb = X + (size_t)b*S_*D_;
#pragma unroll
  for (int i = 0; i < 32; i += 8){
    size_t off = (size_t)(s0+tr+i)*D_ + d0+tc;
    float v = Xb[off];
    tile[tr+i][tc] = v;
    Xf[(size_t)b*S_*D_ + off] = f2h(v);
  }
  __syncthreads();
  uint16_t* XTb = XT + (size_t)b*D_*S_;
#pragma unroll
  for (int i = 0; i < 32; i += 8)
    XTb[(size_t)(d0+tr+i)*S_ + s0+tc] = f2h(tile[tc][tr+i]);
}

// ---- 8-phase NT projection GEMM; Q output pre-scaled by log2(e) ----
// launch_bounds (512,1): grid is 256 blocks = 1/CU anyway; (512,2) was acting
// as a CUDA-style min-BLOCKS hint -> 128-VGPR cap -> acc[8][4] spilled.
__global__ __launch_bounds__(512, 1) void gemm_proj(
    const uint16_t* __restrict__ A, int lda,
    const uint16_t* __restrict__ Bp, int ldb,
    uint16_t* __restrict__ Qo, uint16_t* __restrict__ Ko,
    const float* __restrict__ biasW, const float* __restrict__ biasU,
    int KD)
{
  constexpr int AHALF = 128*128;
  constexpr int BHALF = 128*128;
  constexpr int DSTR  = 2*AHALF + 2*BHALF;
  __shared__ __align__(16) char smem[2*DSTR];

  const int m0 = blockIdx.y * 256;
  const int n0 = blockIdx.x * 256;
  const uint16_t* Apan = A  + (size_t)m0*lda;
  const uint16_t* Bpan = Bp + (size_t)n0*ldb;

  const int t512 = threadIdx.x;
  const int wv   = t512 >> 6;
  const int lane = t512 & 63;
  const int wm   = wv >> 2;
  const int wn   = wv & 3;
  const int fr   = lane & 15;
  const int fg   = lane >> 4;
  const int sw   = fr & 7;

  const int NT = KD >> 6;

  auto Aslot = [&](int par, int h){ return smem + par*DSTR + h*AHALF; };
  auto Bslot = [&](int par, int h){ return smem + par*DSTR + 2*AHALF + h*BHALF; };

  stage_half<128>(Aslot(0,0), Apan,                   lda, wv, lane);
  stage_half<128>(Aslot(0,1), Apan + (size_t)128*lda, lda, wv, lane);
  stage_half<128>(Bslot(0,0), Bpan,                   ldb, wv, lane);
  stage_half<128>(Bslot(0,1), Bpan + (size_t)128*ldb, ldb, wv, lane);
  if (NT > 1)
    stage_half<128>(Aslot(1,0), Apan + 64,            lda, wv, lane);
  asm volatile("s_waitcnt vmcnt(2)" ::: "memory");
  __builtin_amdgcn_s_barrier();

  f32x4 acc[8][4];
#pragma unroll
  for (int i=0;i<8;i++)
#pragma unroll
    for (int j=0;j<4;j++) acc[i][j] = (f32x4){0.f,0.f,0.f,0.f};

  for (int t = 0; t < NT; ++t){
    const int p = t & 1;
    const char* myA = Aslot(p, wm);
    const char* myB = Bslot(p, wn>>1);
    f16x8 af[8];

    auto rdA = [&](int ks){
#pragma unroll
      for (int mf=0; mf<8; ++mf)
        af[mf] = *(const f16x8*)(myA + (mf*16+fr)*128 + (((ks<<2)|fg) ^ sw)*16);
    };
    auto rdB = [&](int ks, int nh, f16x8& b0, f16x8& b1){
      int rb = (wn&1)*64 + nh*32 + fr;
      b0 = *(const f16x8*)(myB + rb*128      + (((ks<<2)|fg) ^ sw)*16);
      b1 = *(const f16x8*)(myB + (rb+16)*128 + (((ks<<2)|fg) ^ sw)*16);
    };
    auto mm = [&](int nh, f16x8 b0, f16x8 b1){
      __builtin_amdgcn_s_setprio(1);
#pragma unroll
      for (int mf=0; mf<8; ++mf){
        acc[mf][nh*2]   = __builtin_amdgcn_mfma_f32_16x16x32_f16(af[mf], b0, acc[mf][nh*2],   0,0,0);
        acc[mf][nh*2+1] = __builtin_amdgcn_mfma_f32_16x16x32_f16(af[mf], b1, acc[mf][nh*2+1], 0,0,0);
      }
      __builtin_amdgcn_s_setprio(0);
    };

    f16x8 b0, b1;
    rdA(0); rdB(0, 0, b0, b1);
    if (t+1 < NT)
      stage_half<128>(Aslot(p^1,1), Apan + (size_t)128*lda + (t+1)*64, lda, wv, lane);
    __builtin_amdgcn_s_barrier();
    mm(0, b0, b1);
    __builtin_amdgcn_s_barrier();
    rdB(0, 1, b0, b1);
    if (t+1 < NT)
      stage_half<128>(Bslot(p^1,0), Bpan + (t+1)*64, ldb, wv, lane);
    __builtin_amdgcn_s_barrier();
    mm(1, b0, b1);
    __builtin_amdgcn_s_barrier();
    rdA(1); rdB(1, 0, b0, b1);
    if (t+1 < NT)
      stage_half<128>(Bslot(p^1,1), Bpan + (size_t)128*ldb + (t+1)*64, ldb, wv, lane);
    __builtin_amdgcn_s_barrier();
    mm(0, b0, b1);
    __builtin_amdgcn_s_barrier();
    rdB(1, 1, b0, b1);
    if (t+2 < NT)
      stage_half<128>(Aslot(p,0), Apan + (t+2)*64, lda, wv, lane);
    __builtin_amdgcn_s_barrier();
    mm(1, b0, b1);
    asm volatile("s_waitcnt vmcnt(2)" ::: "memory");
    __builtin_amdgcn_s_barrier();
  }

#pragma unroll
  for (int mf=0; mf<8; ++mf)
#pragma unroll
    for (int nf=0; nf<4; ++nf){
      int col  = n0 + wn*64 + nf*16 + fr;
      int rowb = m0 + wm*128 + mf*16 + fg*4;
      f32x4 a = acc[mf][nf];
      float bias = (col < U_) ? biasW[col] : biasU[col - U_];
      if (col < U_){
#pragma unroll
        for (int r=0;r<4;r++) Qo[(size_t)(rowb+r)*U_ + col] = f2h((a[r] + bias)*LOG2E);
      } else {
#pragma unroll
        for (int r=0;r<4;r++) Ko[(size_t)(rowb+r)*U_ + col - U_] = f2h(a[r] + bias);
      }
    }
}

// ---- fused flash attention v3 (R7 structure, un-capped registers) ----
// Waves: QK (qh=wv>>2, kh=(wv>>1)&1, ks=wv&1): 32q x 32kv over K-half ks*256..+256,
//        partial S into Ss[ks]; qreg 64 VGPR/wave. 4 indep MFMA chains.
// V: B-frags loaded DIRECTLY from global (L2) into regs.
// PV: wd=wv: 64q x 64d, pa from Ps (swizzled), bv = vreg.
// 3 barriers/iter. launch_bounds (512,1): grid 256 = 1 block/CU; cap 256 VGPR.
__global__ __launch_bounds__(512, 1) void flash_attn(
    const uint16_t* __restrict__ Qf,   // [B*S][512] f16 (pre-scaled by log2e)
    const uint16_t* __restrict__ Kf,   // [B*S][512] f16
    const uint16_t* __restrict__ XT,   // [B][512][2048] f16
    float* __restrict__ Out)           // [B*S][512] f32
{
  __shared__ __align__(16) uint16_t Ks[KVBLK][512];    // 64 KB (granule-swizzled)
  __shared__ __align__(16) float    Ss[2][QBLK][68];   // 34 KB (2 K-half partials)
  __shared__ __align__(16) uint16_t Ps[QBLK][KVBLK];   // 8 KB (granule-swizzled)
  __shared__ float m_s[QBLK], l_s[QBLK], f_s[QBLK];

  const int bid   = blockIdx.x;
  const int batch = bid & 7;
  const int s0    = (bid >> 3) * QBLK;

  const int t    = threadIdx.x;
  const int wv   = t >> 6;
  const int lane = t & 63;
  const int fr   = lane & 15;
  const int fg   = lane >> 4;
  const int qh   = wv >> 2;        // 0..1 QK q-half
  const int kh   = (wv >> 1) & 1;  // 0..1 QK kv-half
  const int ks_  = wv & 1;         // 0..1 QK K-dim half
  const int wd   = wv;             // 0..7 PV d-slice of 64
  const int srow = wv*8 + (lane & 7);   // softmax row
  const int sj   = lane >> 3;           // softmax chunk 0..7

  const uint16_t* Krow = Kf + (size_t)batch*S_*U_;
  const uint16_t* Vt   = XT + (size_t)batch*D_*S_;

  // Q into regs: 32 rows (qh*32..+32), K-dims ks_*256..+256 -> 64 VGPR.
  f16x8 qreg[2][8];
  {
    const uint16_t* Qbase = Qf + ((size_t)batch*S_ + s0 + qh*32)*U_ + ks_*256;
#pragma unroll
    for (int ti=0; ti<2; ++ti)
#pragma unroll
      for (int kk=0; kk<8; ++kk)
        qreg[ti][kk] = *(const f16x8*)(Qbase + (size_t)(ti*16+fr)*U_ + kk*32 + fg*8);
  }

  auto stageK = [&](int ti){
    const uint16_t* src = Krow + (size_t)(ti*KVBLK)*U_;
#pragma unroll
    for (int i=0;i<8;++i){
      int r = i*8 + wv;
      gload16(src + (size_t)r*U_ + ((lane ^ (r&7))<<3),
              (char*)Ks + i*8192 + wv*1024);
    }
  };

  // ---- prologue ----
  stageK(0);
  if (t < QBLK){ m_s[t] = -3e38f; l_s[t] = 0.f; }
  f32x4 acc[4][4];
#pragma unroll
  for (int i=0;i<4;i++)
#pragma unroll
    for (int j=0;j<4;j++) acc[i][j] = (f32x4){0.f,0.f,0.f,0.f};
  asm volatile("s_waitcnt vmcnt(0) lgkmcnt(0)" ::: "memory");
  __builtin_amdgcn_s_barrier();                     // K(0) certified
  __builtin_amdgcn_sched_barrier(0);

  for (int it=0; it<NIT; ++it){
    // ---- QK^T: 32q x 32kv per wave over K-half; 4 indep chains ----
    f32x4 sfr[2][2];
#pragma unroll
    for (int a=0;a<2;a++)
#pragma unroll
      for (int b=0;b<2;b++) sfr[a][b] = (f32x4){0.f,0.f,0.f,0.f};
    {
      const int krow0 = kh*32 + fr;
      const int krow1 = kh*32 + 16 + fr;
      const char* Kb0 = (const char*)Ks + krow0*1024;
      const char* Kb1 = (const char*)Ks + krow1*1024;
      const int swz0 = krow0 & 7, swz1 = krow1 & 7;
      __builtin_amdgcn_s_setprio(1);
#pragma unroll
      for (int kk=0; kk<8; ++kk){
        int g = (ks_<<5) | (kk<<2) | fg;
        f16x8 b0 = *(const f16x8*)(Kb0 + ((g ^ swz0)<<4));
        f16x8 b1 = *(const f16x8*)(Kb1 + ((g ^ swz1)<<4));
        sfr[0][0] = __builtin_amdgcn_mfma_f32_16x16x32_f16(qreg[0][kk], b0, sfr[0][0], 0,0,0);
        sfr[0][1] = __builtin_amdgcn_mfma_f32_16x16x32_f16(qreg[0][kk], b1, sfr[0][1], 0,0,0);
        sfr[1][0] = __builtin_amdgcn_mfma_f32_16x16x32_f16(qreg[1][kk], b0, sfr[1][0], 0,0,0);
        sfr[1][1] = __builtin_amdgcn_mfma_f32_16x16x32_f16(qreg[1][kk], b1, sfr[1][1], 0,0,0);
      }
      __builtin_amdgcn_s_setprio(0);
    }
#pragma unroll
    for (int ti=0; ti<2; ++ti)
#pragma unroll
      for (int kvf=0; kvf<2; ++kvf)
#pragma unroll
        for (int r=0; r<4; ++r)
          Ss[ks_][qh*32 + ti*16 + fg*4 + r][kh*32 + kvf*16 + fr] = sfr[ti][kvf][r];
    asm volatile("s_waitcnt lgkmcnt(0)" ::: "memory");
    __builtin_amdgcn_s_barrier();                   // B1: S partials published
    __builtin_amdgcn_sched_barrier(0);

    // ---- V(it) direct global->reg (issue early, use in PV) ----
    f16x8 vreg[2][4];
#pragma unroll
    for (int vk=0; vk<2; ++vk)
#pragma unroll
      for (int dt=0; dt<4; ++dt)
        vreg[vk][dt] = *(const f16x8*)(Vt + (size_t)(wd*64 + dt*16 + fr)*S_
                                       + it*KVBLK + vk*32 + fg*8);
    stageK((it+1) & (NIT-1));                       // K(t+1) flies under softmax+PV
    __builtin_amdgcn_sched_barrier(0);              // pin issue before softmax

    // ---- online softmax (log2 domain), sum the two K-half partials ----
    {
      float4 a0 = *(const float4*)&Ss[0][srow][sj*8];
      float4 a1 = *(const float4*)&Ss[0][srow][sj*8+4];
      float4 c0 = *(const float4*)&Ss[1][srow][sj*8];
      float4 c1 = *(const float4*)&Ss[1][srow][sj*8+4];
      float v0 = a0.x+c0.x, v1 = a0.y+c0.y, v2 = a0.z+c0.z, v3 = a0.w+c0.w;
      float v4 = a1.x+c1.x, v5 = a1.y+c1.y, v6 = a1.z+c1.z, v7 = a1.w+c1.w;
      float pm = fmaxf(fmaxf(fmaxf(v0,v1),fmaxf(v2,v3)),
                       fmaxf(fmaxf(v4,v5),fmaxf(v6,v7)));
      pm = fmaxf(pm, __shfl_xor(pm, 8));
      pm = fmaxf(pm, __shfl_xor(pm, 16));
      pm = fmaxf(pm, __shfl_xor(pm, 32));
      float mo = m_s[srow];
      float mn = (pm > mo + 11.54f) ? pm : mo;      // defer-max (log2 units)
      float p0 = __builtin_amdgcn_exp2f(v0-mn), p1 = __builtin_amdgcn_exp2f(v1-mn);
      float p2 = __builtin_amdgcn_exp2f(v2-mn), p3 = __builtin_amdgcn_exp2f(v3-mn);
      float p4 = __builtin_amdgcn_exp2f(v4-mn), p5 = __builtin_amdgcn_exp2f(v5-mn);
      float p6 = __builtin_amdgcn_exp2f(v6-mn), p7 = __builtin_amdgcn_exp2f(v7-mn);
      float sum = ((p0+p1)+(p2+p3)) + ((p4+p5)+(p6+p7));
      sum += __shfl_xor(sum, 8);
      sum += __shfl_xor(sum, 16);
      sum += __shfl_xor(sum, 32);
      if (sj == 0){
        float f = __builtin_amdgcn_exp2f(mo - mn);
        f_s[srow] = f;
        m_s[srow] = mn;
        l_s[srow] = l_s[srow]*f + sum;
      }
      uint32_t w0 = (uint32_t)f2h(p0) | ((uint32_t)f2h(p1)<<16);
      uint32_t w1 = (uint32_t)f2h(p2) | ((uint32_t)f2h(p3)<<16);
      uint32_t w2 = (uint32_t)f2h(p4) | ((uint32_t)f2h(p5)<<16);
      uint32_t w3 = (uint32_t)f2h(p6) | ((uint32_t)f2h(p7)<<16);
      uint4 pw = make_uint4(w0,w1,w2,w3);
      *(uint4*)((char*)Ps + srow*128 + ((sj ^ (srow&7))<<4)) = pw;
    }
    asm volatile("s_waitcnt lgkmcnt(0)" ::: "memory");
    __builtin_amdgcn_s_barrier();                   // B2: P + f_s published
    __builtin_amdgcn_sched_barrier(0);

    // ---- O rescale ----
    {
      float fx[4][4];
#pragma unroll
      for (int qt=0; qt<4; ++qt)
#pragma unroll
        for (int r=0; r<4; ++r)
          fx[qt][r] = f_s[qt*16 + fg*4 + r];
      bool nr = false;
#pragma unroll
      for (int qt=0; qt<4; ++qt)
#pragma unroll
        for (int r=0; r<4; ++r) nr = nr | (fx[qt][r] != 1.f);
      if (__any(nr)){
#pragma unroll
        for (int qt=0; qt<4; ++qt)
#pragma unroll
          for (int dt=0; dt<4; ++dt)
#pragma unroll
            for (int r=0; r<4; ++r)
              acc[qt][dt][r] *= fx[qt][r];
      }
    }

    // ---- PV: 64q x 64d per wave; pa from Ps, bv = vreg ----
    __builtin_amdgcn_s_setprio(1);
#pragma unroll
    for (int vk=0; vk<2; ++vk){
      f16x8 pa[4];
#pragma unroll
      for (int qt=0; qt<4; ++qt){
        int q = qt*16 + fr;
        pa[qt] = *(const f16x8*)((const char*)Ps + q*128 + ((((vk<<2)|fg) ^ (q&7))<<4));
      }
#pragma unroll
      for (int qt=0; qt<4; ++qt)
#pragma unroll
        for (int dt=0; dt<4; ++dt)
          acc[qt][dt] = __builtin_amdgcn_mfma_f32_16x16x32_f16(pa[qt], vreg[vk][dt], acc[qt][dt], 0,0,0);
    }
    __builtin_amdgcn_s_setprio(0);
    asm volatile("s_waitcnt vmcnt(0)" ::: "memory"); // K(t+1) landed
    __builtin_amdgcn_s_barrier();                    // B3: PV reads done + K certified
    __builtin_amdgcn_sched_barrier(0);
  }

  // ---- epilogue: O /= l ----
  float linv[4][4];
#pragma unroll
  for (int qt=0; qt<4; ++qt)
#pragma unroll
    for (int r=0; r<4; ++r)
      linv[qt][r] = 1.0f / l_s[qt*16 + fg*4 + r];
  float* Ob = Out + ((size_t)batch*S_ + s0)*D_;
#pragma unroll
  for (int qt=0; qt<4; ++qt)
#pragma unroll
    for (int dt=0; dt<4; ++dt){
      int d = wd*64 + dt*16 + fr;
#pragma unroll
      for (int r=0; r<4; ++r){
        int q = qt*16 + fg*4 + r;
        Ob[(size_t)q*D_ + d] = acc[qt][dt][r] * linv[qt][r];
      }
    }
}

extern "C" void kernel_launch(void* const* d_in, const int* in_sizes, int n_in,
                              void* d_out, int out_size, void* d_ws, size_t ws_size,
                              hipStream_t stream)
{
  (void)in_sizes; (void)n_in; (void)out_size; (void)ws_size;
  const float* X  = (const float*)d_in[0];
  const float* Ww = (const float*)d_in[1];
  const float* Wb = (const float*)d_in[2];
  const float* Uw = (const float*)d_in[3];
  const float* Ub = (const float*)d_in[4];
  float* out = (float*)d_out;

  char* ws = (char*)d_ws;
  size_t off = 0;
  uint16_t* Xf = (uint16_t*)(ws + off); off += (size_t)M_TOTAL*D_*2;  // f16 [M][512]
  uint16_t* XT = (uint16_t*)(ws + off); off += (size_t)B_*D_*S_*2;    // f16 [B][512][2048]
  uint16_t* WT = (uint16_t*)(ws + off); off += (size_t)NPROJ*D_*2;    // f16 [1024][512]
  uint16_t* Qf = (uint16_t*)(ws + off); off += (size_t)M_TOTAL*U_*2;  // f16 [M][512]
  uint16_t* Kf = (uint16_t*)(ws + off); off += (size_t)M_TOTAL*U_*2;

  prep_w<<<dim3((NPROJ*D_)/256), 256, 0, stream>>>(Ww, Uw, WT);
  prep_x<<<dim3(S_/32, D_/32, B_), 256, 0, stream>>>(X, Xf, XT);

  gemm_proj<<<dim3(NPROJ/256, M_TOTAL/256, 1), 512, 0, stream>>>(
      Xf, D_, WT, D_, Qf, Kf, Wb, Ub, D_);

  flash_attn<<<dim3(B_ * (S_/QBLK)), 512, 0, stream>>>(Qf, Kf, XT, out);
}